// Round 4
// baseline (354.147 us; speedup 1.0000x reference)
//
#include <hip/hip_runtime.h>

// Causal self-attention, B=4 T=2048 D=1024 H=16 DK=64.
// cvt(fp32->bf16) -> QKV GEMM (Q pre-scaled by 0.125*log2e; V written
// transposed with sigma-permuted columns) -> flash attn (swapped-operand
// MFMA, QBLK=128: 2 q-subtiles/wave sharing K/V fragments, in-register
// softmax, dbuf + counted vmcnt) -> out GEMM.
//
// sigma bit-shuffle on kv within each 64-block: sigma(k5 k4 k3 k2 k1 k0) =
// (k5 k2 k4 k3 k1 k0). P's register layout after swapped QK^T matches the
// PV B-fragment exactly when V^T columns are stored in sigma^-1 order.

typedef unsigned short u16;
typedef unsigned int   u32;
using bf16x8 = __attribute__((ext_vector_type(8))) short;
using f32x4  = __attribute__((ext_vector_type(4))) float;
using u32x4  = __attribute__((ext_vector_type(4))) u32;

#define DEVINL __device__ __forceinline__
#define AS1 __attribute__((address_space(1)))
#define AS3 __attribute__((address_space(3)))

DEVINL u16 f2bf(float f) {  // round-to-nearest-even
  u32 u = __builtin_bit_cast(u32, f);
  u32 r = u + 0x7fffu + ((u >> 16) & 1u);
  return (u16)(r >> 16);
}
DEVINL u32 cvtpk(float lo, float hi) {  // 2 f32 -> packed 2xbf16, 1 instr
  u32 r;
  asm("v_cvt_pk_bf16_f32 %0, %1, %2" : "=v"(r) : "v"(lo), "v"(hi));
  return r;
}
DEVINL float exp2fast(float x) {
#if __has_builtin(__builtin_amdgcn_exp2f)
  return __builtin_amdgcn_exp2f(x);
#else
  return __builtin_exp2f(x);
#endif
}
DEVINL void gload16(const u16* g, u16* l) {
  __builtin_amdgcn_global_load_lds((const AS1 u32*)g, (AS3 u32*)l, 16, 0, 0);
}

// ---------------- fp32 -> bf16 conversion ----------------
__global__ __launch_bounds__(256) void cvt_f32_bf16(const float* __restrict__ in,
                                                    u16* __restrict__ out, int n4) {
  int i = blockIdx.x * 256 + threadIdx.x;
  if (i < n4) {
    float4 v = reinterpret_cast<const float4*>(in)[i];
    u32 lo = (u32)f2bf(v.x) | ((u32)f2bf(v.y) << 16);
    u32 hi = (u32)f2bf(v.z) | ((u32)f2bf(v.w) << 16);
    reinterpret_cast<uint2*>(out)[i] = make_uint2(lo, hi);
  }
}

// all 4 weight matrices in one launch (outputs contiguous in ws)
__global__ __launch_bounds__(256) void cvt_w4(const float* __restrict__ w0,
                                              const float* __restrict__ w1,
                                              const float* __restrict__ w2,
                                              const float* __restrict__ w3,
                                              u16* __restrict__ o) {
  const int z = blockIdx.y;
  const float* in = (z == 0) ? w0 : (z == 1) ? w1 : (z == 2) ? w2 : w3;
  u16* out = o + (size_t)z * 1048576;
  int i = blockIdx.x * 256 + threadIdx.x;   // 1024 blocks x 256 = 262144 float4
  float4 v = reinterpret_cast<const float4*>(in)[i];
  u32 lo = (u32)f2bf(v.x) | ((u32)f2bf(v.y) << 16);
  u32 hi = (u32)f2bf(v.z) | ((u32)f2bf(v.w) << 16);
  reinterpret_cast<uint2*>(out)[i] = make_uint2(lo, hi);
}

// ---------------- 128x128 NT GEMM core ----------------
DEVINL void gemm_core(const u16* __restrict__ Ag, const u16* __restrict__ Bg,
                      int m0, int n0, f32x4 acc[4][4], u16* Al, u16* Bl, int tid) {
  const int lane = tid & 63, wave = tid >> 6;
  const int wr = wave >> 1, wc = wave & 1;
  const int lr = lane & 15, lg = lane >> 4;
  const int srow = wave * 32 + (lane >> 2);
  const int scol = ((lane & 3) * 8) ^ ((srow & 3) << 3);
  for (int kt = 0; kt < 1024; kt += 32) {
    __syncthreads();
    const u16* ga = Ag + (size_t)(m0 + srow) * 1024 + kt + scol;
    gload16(ga,             Al + wave * 1024);
    gload16(ga + 16 * 1024, Al + wave * 1024 + 512);
    const u16* gb = Bg + (size_t)(n0 + srow) * 1024 + kt + scol;
    gload16(gb,             Bl + wave * 1024);
    gload16(gb + 16 * 1024, Bl + wave * 1024 + 512);
    __syncthreads();
    bf16x8 af[4], bfr[4];
#pragma unroll
    for (int t = 0; t < 4; t++) {
      int ra = wr * 64 + t * 16 + lr;
      af[t] = *reinterpret_cast<const bf16x8*>(
          reinterpret_cast<const char*>(Al) + ra * 64 + ((lg * 16) ^ ((ra & 3) << 4)));
      int rb = wc * 64 + t * 16 + lr;
      bfr[t] = *reinterpret_cast<const bf16x8*>(
          reinterpret_cast<const char*>(Bl) + rb * 64 + ((lg * 16) ^ ((rb & 3) << 4)));
    }
#pragma unroll
    for (int mi = 0; mi < 4; mi++)
#pragma unroll
      for (int ni = 0; ni < 4; ni++)
        acc[mi][ni] = __builtin_amdgcn_mfma_f32_16x16x32_bf16(af[mi], bfr[ni], acc[mi][ni], 0, 0, 0);
  }
}

// QKV projection. z=0: Q*(0.125*log2e) in [B,H,T,DK]. z=1: K in [B,H,T,DK].
// z=2: V^T in [B,H,DK,T] with sigma^-1-permuted t-within-64.
__global__ __launch_bounds__(256) void qkv_gemm(
    const u16* __restrict__ xb,
    const u16* __restrict__ wqb, const u16* __restrict__ wkb, const u16* __restrict__ wvb,
    const float* __restrict__ bq, const float* __restrict__ bk, const float* __restrict__ bv,
    u16* __restrict__ qb, u16* __restrict__ kb, u16* __restrict__ vb) {
  __shared__ __align__(16) u16 smem[8192];
  u16* Al = smem;
  u16* Bl = smem + 4096;
  const int z = blockIdx.z;
  const u16* W = (z == 0) ? wqb : (z == 1) ? wkb : wvb;
  const float* bias = (z == 0) ? bq : (z == 1) ? bk : bv;
  const int m0 = blockIdx.x * 128, n0 = blockIdx.y * 128;
  f32x4 acc[4][4];
#pragma unroll
  for (int a = 0; a < 4; a++)
#pragma unroll
    for (int b2 = 0; b2 < 4; b2++) acc[a][b2] = f32x4{0.f, 0.f, 0.f, 0.f};
  gemm_core(xb, W, m0, n0, acc, Al, Bl, threadIdx.x);
  const int lane = threadIdx.x & 63, wave = threadIdx.x >> 6;
  const int wr = wave >> 1, wc = wave & 1, lr = lane & 15, lg = lane >> 4;

  if (z == 2) {
    const int b = m0 >> 11, tb = m0 & 2047;
#pragma unroll
    for (int h2 = 0; h2 < 2; ++h2) {
      __syncthreads();
      if (wc == h2) {
#pragma unroll
        for (int mi = 0; mi < 4; mi++)
#pragma unroll
          for (int ni = 0; ni < 4; ni++)
#pragma unroll
            for (int i = 0; i < 4; i++) {
              int t_l = wr * 64 + mi * 16 + lg * 4 + i;
              int dk_l = ni * 16 + lr;
              float v = acc[mi][ni][i] + bias[n0 + h2 * 64 + dk_l];
              // column = sigma^-1(t within 64): (m5, m3, m2, m4, m1, m0)
              int m = t_l & 63;
              int col = (t_l & 64) | (m & 0x23) | ((m & 0x0C) << 1) | ((m & 0x10) >> 2);
              *(u16*)((char*)smem + dk_l * 256 + ((col * 2) ^ ((dk_l & 7) << 4))) = f2bf(v);
            }
      }
      __syncthreads();
      const int hh = (n0 >> 6) + h2;
      u16* vrow = vb + (size_t)(b * 16 + hh) * 64 * 2048 + tb;
#pragma unroll
      for (int i2 = 0; i2 < 4; i2++) {
        int c = (int)threadIdx.x + i2 * 256;
        int dk_l = c >> 4, tc2 = c & 15;
        int4 val = *(const int4*)((const char*)smem + dk_l * 256 + ((tc2 * 16) ^ ((dk_l & 7) << 4)));
        *(int4*)(vrow + (size_t)dk_l * 2048 + tc2 * 8) = val;
      }
    }
    return;
  }

  u16* dst = (z == 0) ? qb : kb;
  const float scl = (z == 0) ? 0.180336880f : 1.0f;  // 0.125 * log2(e)
#pragma unroll
  for (int mi = 0; mi < 4; mi++)
#pragma unroll
    for (int ni = 0; ni < 4; ni++)
#pragma unroll
      for (int i = 0; i < 4; i++) {
        int gm = m0 + wr * 64 + mi * 16 + lg * 4 + i;   // b*2048 + t
        int gn = n0 + wc * 64 + ni * 16 + lr;           // h*64 + dk
        float v = (acc[mi][ni][i] + bias[gn]) * scl;
        int b = gm >> 11, t = gm & 2047;
        int h = gn >> 6, dk = gn & 63;
        dst[((size_t)(b * 16 + h) * 2048 + t) * 64 + dk] = f2bf(v);
      }
}

// Output projection: fp32 out = y @ Wo^T + bo.
__global__ __launch_bounds__(256) void out_gemm(
    const u16* __restrict__ yb, const u16* __restrict__ wob,
    const float* __restrict__ bo, float* __restrict__ out) {
  __shared__ __align__(16) u16 smem[8192];
  u16* Al = smem;
  u16* Bl = smem + 4096;
  const int m0 = blockIdx.x * 128, n0 = blockIdx.y * 128;
  f32x4 acc[4][4];
#pragma unroll
  for (int a = 0; a < 4; a++)
#pragma unroll
    for (int b2 = 0; b2 < 4; b2++) acc[a][b2] = f32x4{0.f, 0.f, 0.f, 0.f};
  gemm_core(yb, wob, m0, n0, acc, Al, Bl, threadIdx.x);
  const int lane = threadIdx.x & 63, wave = threadIdx.x >> 6;
  const int wr = wave >> 1, wc = wave & 1, lr = lane & 15, lg = lane >> 4;
#pragma unroll
  for (int mi = 0; mi < 4; mi++)
#pragma unroll
    for (int ni = 0; ni < 4; ni++)
#pragma unroll
      for (int i = 0; i < 4; i++) {
        int gm = m0 + wr * 64 + mi * 16 + lg * 4 + i;
        int gn = n0 + wc * 64 + ni * 16 + lr;
        out[(size_t)gm * 1024 + gn] = acc[mi][ni][i] + bo[gn];
      }
}

// ---------------- causal flash attention (QBLK=128, swapped-operand) --------
// 4 waves; each wave owns 32 q-rows as 2 subtiles (rows q0+s*64+wave*16+lr).
// K/V LDS fragments are read ONCE and shared by both subtiles' MFMAs.
__global__ __launch_bounds__(256) void attn_fwd(const u16* __restrict__ q_ws,
                                                const u16* __restrict__ k_ws,
                                                const u16* __restrict__ vt_ws,
                                                u16* __restrict__ y_ws) {
  __shared__ __align__(16) u16 Kl[2][4096];   // [kv 64][dk 64], swizzled
  __shared__ __align__(16) u16 Vt[2][4096];   // [dk 64][kv 64 sigma-order], swizzled

  const int tid = threadIdx.x;
  const int wave = tid >> 6, lane = tid & 63;
  const int lr = lane & 15, lg = lane >> 4;
  const int qtile = 15 - blockIdx.x;                 // heavy blocks first
  const int bh = blockIdx.y;
  const int q0 = qtile * 128;
  const size_t base = (size_t)bh * 2048 * 64;

  const int srow = wave * 16 + (lane >> 3);
  const int kcol = ((lane & 7) * 8) ^ ((srow & 7) << 3);

  int rgq[2];
  bf16x8 qf[2][2];
#pragma unroll
  for (int s = 0; s < 2; s++) {
    rgq[s] = q0 + s * 64 + wave * 16 + lr;
#pragma unroll
    for (int h = 0; h < 2; h++)
      qf[s][h] = *reinterpret_cast<const bf16x8*>(q_ws + base + (size_t)rgq[s] * 64 + h * 32 + lg * 8);
  }
  asm volatile("s_waitcnt vmcnt(0)" ::: "memory");

  float m_run[2] = {-3.0e38f, -3.0e38f}, l_run[2] = {0.f, 0.f};
  f32x4 oacc[2][4];
#pragma unroll
  for (int s = 0; s < 2; s++)
#pragma unroll
    for (int nt = 0; nt < 4; nt++) oacc[s][nt] = f32x4{0.f, 0.f, 0.f, 0.f};

  auto stage = [&](int buf, int kv0) {
    const u16* kg = k_ws + base + (size_t)(kv0 + srow) * 64 + kcol;
    gload16(kg,           &Kl[buf][wave * 1024]);
    gload16(kg + 8 * 64,  &Kl[buf][wave * 1024 + 512]);
    const u16* vg = vt_ws + base + (size_t)srow * 2048 + kv0 + kcol;
    gload16(vg,            &Vt[buf][wave * 1024]);
    gload16(vg + 8 * 2048, &Vt[buf][wave * 1024 + 512]);
  };

  stage(0, 0);
  const int nt2 = 2 * qtile + 2;
  int cur = 0;
  for (int t2 = 0; t2 < nt2; ++t2) {
    const int kv0 = t2 * 64;
    const bool skip0 = (t2 == nt2 - 1);   // subtile 0 fully masked on last tile
    if (t2 + 1 < nt2) {
      stage(cur ^ 1, kv0 + 64);
      asm volatile("s_waitcnt vmcnt(4)" ::: "memory");
    } else {
      asm volatile("s_waitcnt vmcnt(0)" ::: "memory");
    }
    __builtin_amdgcn_s_barrier();
    const u16* Kb = Kl[cur];
    const u16* Vb = Vt[cur];

    // QK^T for both subtiles, K fragments read once
    f32x4 sA[4], sB[4];
    __builtin_amdgcn_s_setprio(1);
#pragma unroll
    for (int ct = 0; ct < 4; ct++) {
      sA[ct] = f32x4{0.f, 0.f, 0.f, 0.f};
      sB[ct] = f32x4{0.f, 0.f, 0.f, 0.f};
      int krow = ct * 16 + lr;
#pragma unroll
      for (int s2 = 0; s2 < 2; s2++) {
        bf16x8 kf = *reinterpret_cast<const bf16x8*>(
            reinterpret_cast<const char*>(Kb) + krow * 128 + ((s2 * 64 + lg * 16) ^ ((krow & 7) << 4)));
        if (!skip0) sA[ct] = __builtin_amdgcn_mfma_f32_16x16x32_bf16(kf, qf[0][s2], sA[ct], 0, 0, 0);
        sB[ct] = __builtin_amdgcn_mfma_f32_16x16x32_bf16(kf, qf[1][s2], sB[ct], 0, 0, 0);
      }
    }
    __builtin_amdgcn_s_setprio(0);

    // softmax + pack, per subtile (log2 domain; Q pre-scaled)
    u32x4 pw[2][2];
    bool nodefer[2];
#pragma unroll
    for (int s = 0; s < 2; s++) {
      if (s == 0 && skip0) continue;
      float sv[4][4];
#pragma unroll
      for (int ct = 0; ct < 4; ct++)
#pragma unroll
        for (int i = 0; i < 4; i++) sv[ct][i] = (s == 0) ? sA[ct][i] : sB[ct][i];
      if (t2 == 2 * qtile + s) {  // diagonal tile of this subtile
#pragma unroll
        for (int ct = 0; ct < 4; ct++)
#pragma unroll
          for (int i = 0; i < 4; i++)
            if (kv0 + ct * 16 + lg * 4 + i > rgq[s]) sv[ct][i] = -1e30f;
      }
      float cm[4];
#pragma unroll
      for (int ct = 0; ct < 4; ct++)
        cm[ct] = fmaxf(fmaxf(sv[ct][0], sv[ct][1]), fmaxf(sv[ct][2], sv[ct][3]));
      float mx = fmaxf(fmaxf(cm[0], cm[1]), fmaxf(cm[2], cm[3]));
      mx = fmaxf(mx, __shfl_xor(mx, 16, 64));
      mx = fmaxf(mx, __shfl_xor(mx, 32, 64));

      float mnew, alpha;
      nodefer[s] = !__all(mx <= m_run[s] + 8.0f);
      if (nodefer[s]) { mnew = fmaxf(m_run[s], mx); alpha = exp2fast(m_run[s] - mnew); }
      else            { mnew = m_run[s];            alpha = 1.0f; }

      float p[4][4];
#pragma unroll
      for (int ct = 0; ct < 4; ct++)
#pragma unroll
        for (int i = 0; i < 4; i++) p[ct][i] = exp2fast(sv[ct][i] - mnew);
      float cs[4];
#pragma unroll
      for (int ct = 0; ct < 4; ct++)
        cs[ct] = (p[ct][0] + p[ct][1]) + (p[ct][2] + p[ct][3]);
      float ps = (cs[0] + cs[1]) + (cs[2] + cs[3]);
      ps += __shfl_xor(ps, 16, 64);
      ps += __shfl_xor(ps, 32, 64);
      l_run[s] = l_run[s] * alpha + ps;
      m_run[s] = mnew;

#pragma unroll
      for (int ks = 0; ks < 2; ks++) {
        pw[s][ks][0] = cvtpk(p[2 * ks][0],     p[2 * ks][1]);
        pw[s][ks][1] = cvtpk(p[2 * ks][2],     p[2 * ks][3]);
        pw[s][ks][2] = cvtpk(p[2 * ks + 1][0], p[2 * ks + 1][1]);
        pw[s][ks][3] = cvtpk(p[2 * ks + 1][2], p[2 * ks + 1][3]);
      }
      if (nodefer[s]) {
#pragma unroll
        for (int nt = 0; nt < 4; nt++)
#pragma unroll
          for (int i = 0; i < 4; i++) oacc[s][nt][i] *= alpha;
      }
    }

    // PV for both subtiles, V fragments read once
    __builtin_amdgcn_s_setprio(1);
#pragma unroll
    for (int nt = 0; nt < 4; nt++) {
      int d = nt * 16 + lr;
#pragma unroll
      for (int ks = 0; ks < 2; ks++) {
        bf16x8 vf = *reinterpret_cast<const bf16x8*>(
            reinterpret_cast<const char*>(Vb) + d * 128 + ((ks * 64 + lg * 16) ^ ((d & 7) << 4)));
        if (!skip0)
          oacc[0][nt] = __builtin_amdgcn_mfma_f32_16x16x32_bf16(
              vf, __builtin_bit_cast(bf16x8, pw[0][ks]), oacc[0][nt], 0, 0, 0);
        oacc[1][nt] = __builtin_amdgcn_mfma_f32_16x16x32_bf16(
            vf, __builtin_bit_cast(bf16x8, pw[1][ks]), oacc[1][nt], 0, 0, 0);
      }
    }
    __builtin_amdgcn_s_setprio(0);
    __builtin_amdgcn_s_barrier();
    cur ^= 1;
  }

  // epilogue
  const int b = bh >> 4, h = bh & 15;
#pragma unroll
  for (int s = 0; s < 2; s++) {
    const float inv = 1.0f / l_run[s];
#pragma unroll
    for (int nt = 0; nt < 4; nt++) {
      u32 w0 = (u32)f2bf(oacc[s][nt][0] * inv) | ((u32)f2bf(oacc[s][nt][1] * inv) << 16);
      u32 w1 = (u32)f2bf(oacc[s][nt][2] * inv) | ((u32)f2bf(oacc[s][nt][3] * inv) << 16);
      *reinterpret_cast<uint2*>(y_ws + ((size_t)(b * 2048 + rgq[s])) * 1024 + h * 64 + nt * 16 + lg * 4) =
          make_uint2(w0, w1);
    }
  }
}

// ---------------- launch ----------------
extern "C" void kernel_launch(void* const* d_in, const int* in_sizes, int n_in,
                              void* d_out, int out_size, void* d_ws, size_t ws_size,
                              hipStream_t stream) {
  const float* x  = (const float*)d_in[0];
  const float* Wq = (const float*)d_in[2];
  const float* bq = (const float*)d_in[3];
  const float* Wk = (const float*)d_in[4];
  const float* bk = (const float*)d_in[5];
  const float* Wv = (const float*)d_in[6];
  const float* bv = (const float*)d_in[7];
  const float* Wo = (const float*)d_in[8];
  const float* bo = (const float*)d_in[9];
  float* out = (float*)d_out;

  u16* xb  = (u16*)d_ws;           // 8192*1024
  u16* wqb = xb  + 8388608;        // 4 weight mats contiguous
  u16* wkb = wqb + 1048576;
  u16* wvb = wkb + 1048576;
  u16* wob = wvb + 1048576;
  u16* qb  = wob + 1048576;        // [B,H,T,DK], pre-scaled
  u16* kb  = qb  + 8388608;        // [B,H,T,DK]
  u16* vtb = kb  + 8388608;        // [B,H,DK,T], sigma-permuted columns
  u16* yb  = vtb + 8388608;        // [B,T,D]

  cvt_f32_bf16<<<8192, 256, 0, stream>>>(x, xb, 2097152);
  cvt_w4<<<dim3(1024, 4), 256, 0, stream>>>(Wq, Wk, Wv, Wo, wqb);

  qkv_gemm<<<dim3(64, 8, 3), 256, 0, stream>>>(xb, wqb, wkb, wvb, bq, bk, bv, qb, kb, vtb);
  attn_fwd<<<dim3(16, 64), 256, 0, stream>>>(qb, kb, vtb, yb);
  out_gemm<<<dim3(64, 8), 256, 0, stream>>>(yb, wob, bo, out);
}

// Round 6
// 315.176 us; speedup vs baseline: 1.1236x; 1.1236x over previous
//
#include <hip/hip_runtime.h>

// Causal self-attention, B=4 T=2048 D=1024 H=16 DK=64.
// cvt(fp32->bf16) -> QKV GEMM (Q pre-scaled by 0.125*log2e; V written
// transposed with sigma-permuted columns) -> flash attn (QBLK=64,
// swapped-operand MFMA, in-register softmax w/ lane-local defer-max fast
// path + l-via-MFMA ones trick, dbuf + counted vmcnt) -> out GEMM.
//
// sigma bit-shuffle on kv within each 64-block: sigma(k5 k4 k3 k2 k1 k0) =
// (k5 k2 k4 k3 k1 k0). P's register layout after swapped QK^T matches the
// PV B-fragment exactly when V^T columns are stored in sigma^-1 order.

typedef unsigned short u16;
typedef unsigned int   u32;
using bf16x8 = __attribute__((ext_vector_type(8))) short;
using f32x4  = __attribute__((ext_vector_type(4))) float;
using u32x4  = __attribute__((ext_vector_type(4))) u32;

#define DEVINL __device__ __forceinline__
#define AS1 __attribute__((address_space(1)))
#define AS3 __attribute__((address_space(3)))

DEVINL u16 f2bf(float f) {  // round-to-nearest-even
  u32 u = __builtin_bit_cast(u32, f);
  u32 r = u + 0x7fffu + ((u >> 16) & 1u);
  return (u16)(r >> 16);
}
DEVINL u32 cvtpk(float lo, float hi) {  // 2 f32 -> packed 2xbf16, 1 instr
  u32 r;
  asm("v_cvt_pk_bf16_f32 %0, %1, %2" : "=v"(r) : "v"(lo), "v"(hi));
  return r;
}
DEVINL float exp2fast(float x) {
#if __has_builtin(__builtin_amdgcn_exp2f)
  return __builtin_amdgcn_exp2f(x);
#else
  return __builtin_exp2f(x);
#endif
}
DEVINL void gload16(const u16* g, u16* l) {
  __builtin_amdgcn_global_load_lds((const AS1 u32*)g, (AS3 u32*)l, 16, 0, 0);
}

// ---------------- fp32 -> bf16 conversion ----------------
__global__ __launch_bounds__(256) void cvt_f32_bf16(const float* __restrict__ in,
                                                    u16* __restrict__ out, int n4) {
  int i = blockIdx.x * 256 + threadIdx.x;
  if (i < n4) {
    float4 v = reinterpret_cast<const float4*>(in)[i];
    u32 lo = (u32)f2bf(v.x) | ((u32)f2bf(v.y) << 16);
    u32 hi = (u32)f2bf(v.z) | ((u32)f2bf(v.w) << 16);
    reinterpret_cast<uint2*>(out)[i] = make_uint2(lo, hi);
  }
}

// all 4 weight matrices in one launch (outputs contiguous in ws)
__global__ __launch_bounds__(256) void cvt_w4(const float* __restrict__ w0,
                                              const float* __restrict__ w1,
                                              const float* __restrict__ w2,
                                              const float* __restrict__ w3,
                                              u16* __restrict__ o) {
  const int z = blockIdx.y;
  const float* in = (z == 0) ? w0 : (z == 1) ? w1 : (z == 2) ? w2 : w3;
  u16* out = o + (size_t)z * 1048576;
  int i = blockIdx.x * 256 + threadIdx.x;   // 1024 blocks x 256 = 262144 float4
  float4 v = reinterpret_cast<const float4*>(in)[i];
  u32 lo = (u32)f2bf(v.x) | ((u32)f2bf(v.y) << 16);
  u32 hi = (u32)f2bf(v.z) | ((u32)f2bf(v.w) << 16);
  reinterpret_cast<uint2*>(out)[i] = make_uint2(lo, hi);
}

// ---------------- 128x128 NT GEMM core ----------------
DEVINL void gemm_core(const u16* __restrict__ Ag, const u16* __restrict__ Bg,
                      int m0, int n0, f32x4 acc[4][4], u16* Al, u16* Bl, int tid) {
  const int lane = tid & 63, wave = tid >> 6;
  const int wr = wave >> 1, wc = wave & 1;
  const int lr = lane & 15, lg = lane >> 4;
  const int srow = wave * 32 + (lane >> 2);
  const int scol = ((lane & 3) * 8) ^ ((srow & 3) << 3);
  for (int kt = 0; kt < 1024; kt += 32) {
    __syncthreads();
    const u16* ga = Ag + (size_t)(m0 + srow) * 1024 + kt + scol;
    gload16(ga,             Al + wave * 1024);
    gload16(ga + 16 * 1024, Al + wave * 1024 + 512);
    const u16* gb = Bg + (size_t)(n0 + srow) * 1024 + kt + scol;
    gload16(gb,             Bl + wave * 1024);
    gload16(gb + 16 * 1024, Bl + wave * 1024 + 512);
    __syncthreads();
    bf16x8 af[4], bfr[4];
#pragma unroll
    for (int t = 0; t < 4; t++) {
      int ra = wr * 64 + t * 16 + lr;
      af[t] = *reinterpret_cast<const bf16x8*>(
          reinterpret_cast<const char*>(Al) + ra * 64 + ((lg * 16) ^ ((ra & 3) << 4)));
      int rb = wc * 64 + t * 16 + lr;
      bfr[t] = *reinterpret_cast<const bf16x8*>(
          reinterpret_cast<const char*>(Bl) + rb * 64 + ((lg * 16) ^ ((rb & 3) << 4)));
    }
#pragma unroll
    for (int mi = 0; mi < 4; mi++)
#pragma unroll
      for (int ni = 0; ni < 4; ni++)
        acc[mi][ni] = __builtin_amdgcn_mfma_f32_16x16x32_bf16(af[mi], bfr[ni], acc[mi][ni], 0, 0, 0);
  }
}

// QKV projection. z=0: Q*(0.125*log2e) in [B,H,T,DK]. z=1: K in [B,H,T,DK].
// z=2: V^T in [B,H,DK,T] with sigma^-1-permuted t-within-64.
__global__ __launch_bounds__(256) void qkv_gemm(
    const u16* __restrict__ xb,
    const u16* __restrict__ wqb, const u16* __restrict__ wkb, const u16* __restrict__ wvb,
    const float* __restrict__ bq, const float* __restrict__ bk, const float* __restrict__ bv,
    u16* __restrict__ qb, u16* __restrict__ kb, u16* __restrict__ vb) {
  __shared__ __align__(16) u16 smem[8192];
  u16* Al = smem;
  u16* Bl = smem + 4096;
  const int z = blockIdx.z;
  const u16* W = (z == 0) ? wqb : (z == 1) ? wkb : wvb;
  const float* bias = (z == 0) ? bq : (z == 1) ? bk : bv;
  const int m0 = blockIdx.x * 128, n0 = blockIdx.y * 128;
  f32x4 acc[4][4];
#pragma unroll
  for (int a = 0; a < 4; a++)
#pragma unroll
    for (int b2 = 0; b2 < 4; b2++) acc[a][b2] = f32x4{0.f, 0.f, 0.f, 0.f};
  gemm_core(xb, W, m0, n0, acc, Al, Bl, threadIdx.x);
  const int lane = threadIdx.x & 63, wave = threadIdx.x >> 6;
  const int wr = wave >> 1, wc = wave & 1, lr = lane & 15, lg = lane >> 4;

  if (z == 2) {
    const int b = m0 >> 11, tb = m0 & 2047;
#pragma unroll
    for (int h2 = 0; h2 < 2; ++h2) {
      __syncthreads();
      if (wc == h2) {
#pragma unroll
        for (int mi = 0; mi < 4; mi++)
#pragma unroll
          for (int ni = 0; ni < 4; ni++)
#pragma unroll
            for (int i = 0; i < 4; i++) {
              int t_l = wr * 64 + mi * 16 + lg * 4 + i;
              int dk_l = ni * 16 + lr;
              float v = acc[mi][ni][i] + bias[n0 + h2 * 64 + dk_l];
              // column = sigma^-1(t within 64): (m5, m3, m2, m4, m1, m0)
              int m = t_l & 63;
              int col = (t_l & 64) | (m & 0x23) | ((m & 0x0C) << 1) | ((m & 0x10) >> 2);
              *(u16*)((char*)smem + dk_l * 256 + ((col * 2) ^ ((dk_l & 7) << 4))) = f2bf(v);
            }
      }
      __syncthreads();
      const int hh = (n0 >> 6) + h2;
      u16* vrow = vb + (size_t)(b * 16 + hh) * 64 * 2048 + tb;
#pragma unroll
      for (int i2 = 0; i2 < 4; i2++) {
        int c = (int)threadIdx.x + i2 * 256;
        int dk_l = c >> 4, tc2 = c & 15;
        int4 val = *(const int4*)((const char*)smem + dk_l * 256 + ((tc2 * 16) ^ ((dk_l & 7) << 4)));
        *(int4*)(vrow + (size_t)dk_l * 2048 + tc2 * 8) = val;
      }
    }
    return;
  }

  u16* dst = (z == 0) ? qb : kb;
  const float scl = (z == 0) ? 0.180336880f : 1.0f;  // 0.125 * log2(e)
#pragma unroll
  for (int mi = 0; mi < 4; mi++)
#pragma unroll
    for (int ni = 0; ni < 4; ni++)
#pragma unroll
      for (int i = 0; i < 4; i++) {
        int gm = m0 + wr * 64 + mi * 16 + lg * 4 + i;   // b*2048 + t
        int gn = n0 + wc * 64 + ni * 16 + lr;           // h*64 + dk
        float v = (acc[mi][ni][i] + bias[gn]) * scl;
        int b = gm >> 11, t = gm & 2047;
        int h = gn >> 6, dk = gn & 63;
        dst[((size_t)(b * 16 + h) * 2048 + t) * 64 + dk] = f2bf(v);
      }
}

// Output projection: fp32 out = y @ Wo^T + bo.
__global__ __launch_bounds__(256) void out_gemm(
    const u16* __restrict__ yb, const u16* __restrict__ wob,
    const float* __restrict__ bo, float* __restrict__ out) {
  __shared__ __align__(16) u16 smem[8192];
  u16* Al = smem;
  u16* Bl = smem + 4096;
  const int m0 = blockIdx.x * 128, n0 = blockIdx.y * 128;
  f32x4 acc[4][4];
#pragma unroll
  for (int a = 0; a < 4; a++)
#pragma unroll
    for (int b2 = 0; b2 < 4; b2++) acc[a][b2] = f32x4{0.f, 0.f, 0.f, 0.f};
  gemm_core(yb, wob, m0, n0, acc, Al, Bl, threadIdx.x);
  const int lane = threadIdx.x & 63, wave = threadIdx.x >> 6;
  const int wr = wave >> 1, wc = wave & 1, lr = lane & 15, lg = lane >> 4;
#pragma unroll
  for (int mi = 0; mi < 4; mi++)
#pragma unroll
    for (int ni = 0; ni < 4; ni++)
#pragma unroll
      for (int i = 0; i < 4; i++) {
        int gm = m0 + wr * 64 + mi * 16 + lg * 4 + i;
        int gn = n0 + wc * 64 + ni * 16 + lr;
        out[(size_t)gm * 1024 + gn] = acc[mi][ni][i] + bo[gn];
      }
}

// ---------------- causal flash attention (QBLK=64, swapped-operand) ---------
// 4 waves x 16 q-rows. Per lane: q = lane&15 (one row), 16 kv values/tile.
// S^T = mfma(K, Q); O^T = mfma(V^T, P); l = mfma(ones, P) (ones-row trick).
// Steady state: lane-local max check only (no cross-lane reduce, no rescale).
__global__ __launch_bounds__(256) void attn_fwd(const u16* __restrict__ q_ws,
                                                const u16* __restrict__ k_ws,
                                                const u16* __restrict__ vt_ws,
                                                u16* __restrict__ y_ws) {
  __shared__ __align__(16) u16 Kl[2][4096];   // [kv 64][dk 64], swizzled
  __shared__ __align__(16) u16 Vt[2][4096];   // [dk 64][kv 64 sigma-order], swizzled

  const int tid = threadIdx.x;
  const int wave = tid >> 6, lane = tid & 63;
  const int lr = lane & 15, lg = lane >> 4;
  const int qtile = 31 - blockIdx.x;                 // heavy blocks first
  const int bh = blockIdx.y;
  const int q0 = qtile * 64;
  const size_t base = (size_t)bh * 2048 * 64;
  const int rgq = q0 + wave * 16 + lr;               // this lane's q-row

  const int srow = wave * 16 + (lane >> 3);
  const int kcol = ((lane & 7) * 8) ^ ((srow & 7) << 3);

  // Q fragments (pre-scaled by 0.125*log2e at projection time)
  bf16x8 qf[2];
#pragma unroll
  for (int s = 0; s < 2; s++)
    qf[s] = *reinterpret_cast<const bf16x8*>(q_ws + base + (size_t)rgq * 64 + s * 32 + lg * 8);
  asm volatile("s_waitcnt vmcnt(0)" ::: "memory");

  const u32x4 onesw = {0x3F803F80u, 0x3F803F80u, 0x3F803F80u, 0x3F803F80u};
  const bf16x8 onesf = __builtin_bit_cast(bf16x8, onesw);

  float m_run = -3.0e38f;
  f32x4 lacc = f32x4{0.f, 0.f, 0.f, 0.f};    // row-sum accumulator via MFMA
  f32x4 oacc[4];
#pragma unroll
  for (int nt = 0; nt < 4; nt++) oacc[nt] = f32x4{0.f, 0.f, 0.f, 0.f};

  auto stage = [&](int buf, int kv0) {
    const u16* kg = k_ws + base + (size_t)(kv0 + srow) * 64 + kcol;
    gload16(kg,           &Kl[buf][wave * 1024]);
    gload16(kg + 8 * 64,  &Kl[buf][wave * 1024 + 512]);
    const u16* vg = vt_ws + base + (size_t)srow * 2048 + kv0 + kcol;
    gload16(vg,            &Vt[buf][wave * 1024]);
    gload16(vg + 8 * 2048, &Vt[buf][wave * 1024 + 512]);
  };

  stage(0, 0);
  int cur = 0;
  for (int t2 = 0; t2 <= qtile; ++t2) {
    const int kv0 = t2 * 64;
    if (t2 < qtile) {
      stage(cur ^ 1, kv0 + 64);
      asm volatile("s_waitcnt vmcnt(4)" ::: "memory");
    } else {
      asm volatile("s_waitcnt vmcnt(0)" ::: "memory");
    }
    __builtin_amdgcn_s_barrier();
    const u16* Kb = Kl[cur];
    const u16* Vb = Vt[cur];

    // S^T tile: lane holds S[q=rgq][kv0 + ct*16 + lg*4 + i] (log2-domain)
    float sv[4][4];
    __builtin_amdgcn_s_setprio(1);
#pragma unroll
    for (int ct = 0; ct < 4; ct++) {
      f32x4 s = f32x4{0.f, 0.f, 0.f, 0.f};
      int krow = ct * 16 + lr;
#pragma unroll
      for (int s2 = 0; s2 < 2; s2++) {
        bf16x8 kf = *reinterpret_cast<const bf16x8*>(
            reinterpret_cast<const char*>(Kb) + krow * 128 + ((s2 * 64 + lg * 16) ^ ((krow & 7) << 4)));
        s = __builtin_amdgcn_mfma_f32_16x16x32_bf16(kf, qf[s2], s, 0, 0, 0);
      }
#pragma unroll
      for (int i = 0; i < 4; i++) sv[ct][i] = s[i];
    }
    __builtin_amdgcn_s_setprio(0);

    if (t2 == qtile) {  // causal mask only on the diagonal tile
#pragma unroll
      for (int ct = 0; ct < 4; ct++)
#pragma unroll
        for (int i = 0; i < 4; i++)
          if (kv0 + ct * 16 + lg * 4 + i > rgq) sv[ct][i] = -1e30f;
    }

    // lane-local max; cross-lane reduce + rescale only if defer bound violated
    float cm[4];
#pragma unroll
    for (int ct = 0; ct < 4; ct++)
      cm[ct] = fmaxf(fmaxf(sv[ct][0], sv[ct][1]), fmaxf(sv[ct][2], sv[ct][3]));
    float mx = fmaxf(fmaxf(cm[0], cm[1]), fmaxf(cm[2], cm[3]));
    const bool viol = !__all(mx <= m_run + 8.0f);
    float mnew = m_run;
    if (viol) {
      mx = fmaxf(mx, __shfl_xor(mx, 16, 64));
      mx = fmaxf(mx, __shfl_xor(mx, 32, 64));
      mnew = fmaxf(m_run, mx);
      float alpha = exp2fast(m_run - mnew);
#pragma unroll
      for (int nt = 0; nt < 4; nt++)
#pragma unroll
        for (int i = 0; i < 4; i++) oacc[nt][i] *= alpha;
#pragma unroll
      for (int i = 0; i < 4; i++) lacc[i] *= alpha;
      m_run = mnew;
    }

    // P = exp2(S - m) and pack into PV B-fragments (lane-local thanks to sigma)
    float p[4][4];
#pragma unroll
    for (int ct = 0; ct < 4; ct++)
#pragma unroll
      for (int i = 0; i < 4; i++) p[ct][i] = exp2fast(sv[ct][i] - mnew);
    u32x4 pw[2];
#pragma unroll
    for (int ks = 0; ks < 2; ks++) {
      pw[ks][0] = cvtpk(p[2 * ks][0],     p[2 * ks][1]);
      pw[ks][1] = cvtpk(p[2 * ks][2],     p[2 * ks][3]);
      pw[ks][2] = cvtpk(p[2 * ks + 1][0], p[2 * ks + 1][1]);
      pw[ks][3] = cvtpk(p[2 * ks + 1][2], p[2 * ks + 1][3]);
    }

    // O^T += V^T @ P ; l += ones @ P
    __builtin_amdgcn_s_setprio(1);
#pragma unroll
    for (int nt = 0; nt < 4; nt++) {
      int d = nt * 16 + lr;
#pragma unroll
      for (int ks = 0; ks < 2; ks++) {
        bf16x8 vf = *reinterpret_cast<const bf16x8*>(
            reinterpret_cast<const char*>(Vb) + d * 128 + ((ks * 64 + lg * 16) ^ ((d & 7) << 4)));
        oacc[nt] = __builtin_amdgcn_mfma_f32_16x16x32_bf16(
            vf, __builtin_bit_cast(bf16x8, pw[ks]), oacc[nt], 0, 0, 0);
      }
    }
    lacc = __builtin_amdgcn_mfma_f32_16x16x32_bf16(
        onesf, __builtin_bit_cast(bf16x8, pw[0]), lacc, 0, 0, 0);
    lacc = __builtin_amdgcn_mfma_f32_16x16x32_bf16(
        onesf, __builtin_bit_cast(bf16x8, pw[1]), lacc, 0, 0, 0);
    __builtin_amdgcn_s_setprio(0);
    __builtin_amdgcn_s_barrier();
    cur ^= 1;
  }

  // epilogue: y[b, rgq, h*64 + nt*16 + lg*4 + i] = O^T[...][rgq] / l
  const float inv = 1.0f / lacc[0];
  const int b = bh >> 4, h = bh & 15;
#pragma unroll
  for (int nt = 0; nt < 4; nt++) {
    u32 w0 = cvtpk(oacc[nt][0] * inv, oacc[nt][1] * inv);
    u32 w1 = cvtpk(oacc[nt][2] * inv, oacc[nt][3] * inv);
    *reinterpret_cast<uint2*>(y_ws + ((size_t)(b * 2048 + rgq)) * 1024 + h * 64 + nt * 16 + lg * 4) =
        make_uint2(w0, w1);
  }
}

// ---------------- launch ----------------
extern "C" void kernel_launch(void* const* d_in, const int* in_sizes, int n_in,
                              void* d_out, int out_size, void* d_ws, size_t ws_size,
                              hipStream_t stream) {
  const float* x  = (const float*)d_in[0];
  const float* Wq = (const float*)d_in[2];
  const float* bq = (const float*)d_in[3];
  const float* Wk = (const float*)d_in[4];
  const float* bk = (const float*)d_in[5];
  const float* Wv = (const float*)d_in[6];
  const float* bv = (const float*)d_in[7];
  const float* Wo = (const float*)d_in[8];
  const float* bo = (const float*)d_in[9];
  float* out = (float*)d_out;

  u16* xb  = (u16*)d_ws;           // 8192*1024
  u16* wqb = xb  + 8388608;        // 4 weight mats contiguous
  u16* wkb = wqb + 1048576;
  u16* wvb = wkb + 1048576;
  u16* wob = wvb + 1048576;
  u16* qb  = wob + 1048576;        // [B,H,T,DK], pre-scaled
  u16* kb  = qb  + 8388608;        // [B,H,T,DK]
  u16* vtb = kb  + 8388608;        // [B,H,DK,T], sigma-permuted columns
  u16* yb  = vtb + 8388608;        // [B,T,D]

  cvt_f32_bf16<<<8192, 256, 0, stream>>>(x, xb, 2097152);
  cvt_w4<<<dim3(1024, 4), 256, 0, stream>>>(Wq, Wk, Wv, Wo, wqb);

  qkv_gemm<<<dim3(64, 8, 3), 256, 0, stream>>>(xb, wqb, wkb, wvb, bq, bk, bv, qb, kb, vtb);
  attn_fwd<<<dim3(32, 64), 256, 0, stream>>>(qb, kb, vtb, yb);
  out_gemm<<<dim3(64, 8), 256, 0, stream>>>(yb, wob, bo, out);
}